// Round 6
// baseline (107.617 us; speedup 1.0000x reference)
//
#include <hip/hip_runtime.h>
#include <hip/hip_cooperative_groups.h>
#include <math.h>

namespace cg = cooperative_groups;

// Preisach hysteresis, N=256, parallel-in-time clamp-scan, ONE cooperative
// dispatch.
//
// Per row r the state is a staircase: +1 for j<=c_r, -1 for c_r<j<=r.
// Step update: c = max(min(c, k_t), r_t) with
//   up   (h>hp): k=256, r_t = (row < u_t ? row : -1), u_t = #{i : i*d < h}
//   down (h<hp): k = max{j : j*d <= h}, r_t = -1
// Clamps compose: chunk of steps == c -> max(min(c,HI),LO), (LO,HI) = chunk
// run on seeds (-1, 256).
//
// Block i <-> chunk i (32 steps).  Phase 1: wave 0 builds chunk codes into
// LDS (never leave the block); each wave composes (LO,HI) for 64 rows
// (1 row/lane) -> global lohi; block i also builds packed G column i
// (4 waves x 1 row, 10 shuffle-scan segments/block).  grid.sync().
// Phase 2: stage G to LDS (256 threads), entry scan (i iters x 1 coalesced
// int2/lane), 32-step replay (1 gather/lane/step, lane-private bank) +
// 64-lane butterfly; 4 wave-partials combined via 512 B LDS. No atomics.
//
// Packed G column i holds rows {i, 255-i, 64+i, 191-i} = exactly 518 floats:
//   row i     : idx0 = 0        row 255-i : idx0 = i+2
//   row 64+i  : idx0 = 259      row 191-i : idx0 = 325+i
// addr = idx*64 + col.  G_r[e] = 2*P_r(e-1) - Tot_r, e in [0, r+1],
// P = prefix sums of softplus(raw row r).

#define CL 32               // chunk length (time steps)
#define GSZ (518 * 64)      // packed G table, floats (132608 B)

__device__ __forceinline__ int make_code(const float* __restrict__ h, int t, int T) {
    const float delta = 1.0f / 255.0f;          // fl(1/255), matches jnp.linspace
    int code = 256;                              // no-op: k=256, u=0
    if (t < T) {
        const float hc = h[t];
        const float hp = (t == 0) ? 0.0f : h[t - 1];
        if (hc > hp) {
            // u-1 = max{ i : (float)i*delta < hc }   (yy >= h keeps state)
            int i2 = (int)(hc * 255.0f);
            if (i2 > 255) i2 = 255;
            while (i2 < 255 && (float)(i2 + 1) * delta < hc) ++i2;
            while (i2 >= 0 && (float)i2 * delta >= hc) --i2;
            code = ((i2 + 1) << 16) | 256;
        } else if (hc < hp) {
            // k = max{ j : (float)j*delta <= hc }    (xx <= h keeps state)
            int kk = (int)(hc * 255.0f);
            if (kk > 255) kk = 255;
            while (kk < 255 && (float)(kk + 1) * delta <= hc) ++kk;
            while (kk > 0 && (float)kk * delta > hc) --kk;
            code = kk;
        }
    }
    return code;
}

__global__ __launch_bounds__(256)
void hyst_fused(const float* __restrict__ h, const float* __restrict__ raw,
                const float* __restrict__ scale, const float* __restrict__ offset,
                float* __restrict__ out, int2* __restrict__ lohi,
                float* __restrict__ Gg, int T, int NCH) {
    __shared__ __align__(16) float Gl[GSZ];      // 132608 B
    __shared__ int cds[CL];                      // chunk codes (this block)
    __shared__ float cb[4 * CL];                 // per-wave step partials

    const int i = blockIdx.x;
    const int tid = threadIdx.x;
    const int w = tid >> 6, l = tid & 63;
    const int r = 64 * w + l;                    // this thread's row (phase 1b/2)

    // ---- phase 1a: codes for chunk i (wave 0, lanes < CL)
    if (i < NCH && w == 0 && l < CL)
        cds[l] = make_code(h, i * CL + l, T);
    __syncthreads();

    // ---- phase 1b: compose (LO,HI) for row r over chunk i's 32 steps
    if (i < NCH) {
        int lo = -1, hi = 256;                   // identity clamp on [-1,255]
        #pragma unroll
        for (int s = 0; s < CL; ++s) {
            const int cd = cds[s];               // uniform -> LDS broadcast
            const int k = cd & 0xFFFF, u = cd >> 16;
            const int rr = (r < u) ? r : -1;
            lo = max(min(lo, k), rr);
            hi = max(min(hi, k), rr);
        }
        lohi[i * 256 + r] = make_int2(lo, hi);   // coalesced per wave
    }

    // ---- phase 1c: G build, packed column i (blocks 0..63), wave w -> 1 row
    if (i < 64) {
        int gr, idx0;
        if (w == 0)      { gr = i;       idx0 = 0; }
        else if (w == 1) { gr = 255 - i; idx0 = i + 2; }
        else if (w == 2) { gr = 64 + i;  idx0 = 259; }
        else             { gr = 191 - i; idx0 = 325 + i; }
        const int tri = gr * (gr + 1) / 2;
        float Pseg[4];
        float carry = 0.0f;
        const int nseg = gr / 64 + 1;
        #pragma unroll
        for (int s = 0; s < 4; ++s) {
            Pseg[s] = 0.0f;
            if (s < nseg) {
                const int j = s * 64 + l;
                float v = 0.0f;
                if (j <= gr) {
                    const float x = raw[tri + j];
                    // jax.nn.softplus(x) = max(x,0) + log1p(exp(-|x|))
                    v = fmaxf(x, 0.0f) + log1pf(expf(-fabsf(x)));
                }
                #pragma unroll
                for (int off = 1; off < 64; off <<= 1) {
                    const float t2 = __shfl_up(v, off);
                    if (l >= off) v += t2;
                }
                Pseg[s] = carry + v;             // inclusive prefix P_j
                carry += __shfl(v, 63);          // segment total
            }
        }
        const float tot = carry;
        if (l == 0) Gg[idx0 * 64 + i] = -tot;    // e=0: 2*P(-1) - Tot
        #pragma unroll
        for (int s = 0; s < 4; ++s) {
            const int j = s * 64 + l;
            if (j <= gr) Gg[(idx0 + 1 + j) * 64 + i] = 2.0f * Pseg[s] - tot;
        }
    }

    cg::this_grid().sync();                      // Gg + lohi globally visible

    // ---- phase 2: evaluate chunk i
    if (i < NCH) {
        // stage G: coalesced float4 copy, all 256 threads (8288 vec4)
        {
            const float4* __restrict__ Gf4 = (const float4*)Gg;
            float4* Gl4 = (float4*)Gl;
            #pragma unroll 4
            for (int j = tid; j < GSZ / 4; j += 256) Gl4[j] = Gf4[j];
        }

        // entry state for row r: compose prior chunks (independent loads)
        int c = -1;
        #pragma unroll 4
        for (int j = 0; j < i; ++j) {
            const int2 lh = lohi[j * 256 + r];
            c = max(min(c, lh.y), lh.x);
        }
        __syncthreads();                         // staging done

        // gather address: Gl[(gbase + c)*64 + lcol], lane-private bank (2-way)
        int gbase, lcol;
        if (w == 0)      { gbase = 1;        lcol = l; }
        else if (w == 1) { gbase = 260;      lcol = l; }
        else if (w == 2) { gbase = 389 - l;  lcol = 63 - l; }
        else             { gbase = 66 - l;   lcol = 63 - l; }

        float myout = 0.0f;
        #pragma unroll 4
        for (int s = 0; s < CL; ++s) {
            const int cd = cds[s];
            const int k = cd & 0xFFFF, u = cd >> 16;
            c = max(min(c, k), (r < u) ? r : -1);
            float p = Gl[(gbase + c) * 64 + lcol];
            #pragma unroll
            for (int off = 32; off; off >>= 1) p += __shfl_xor(p, off);
            if (l == s) myout = p;               // lane s keeps step s (wave sum)
        }
        if (l < CL) cb[w * CL + l] = myout;
        __syncthreads();
        if (w == 0 && l < CL) {
            const int t = i * CL + l;
            if (t < T) {
                const float sum = cb[l] + cb[CL + l] + cb[2 * CL + l] + cb[3 * CL + l];
                out[t] = sum * (1.0f / 32896.0f) * scale[0] + offset[0];
            }
        }
    }
}

extern "C" void kernel_launch(void* const* d_in, const int* in_sizes, int n_in,
                              void* d_out, int out_size, void* d_ws, size_t ws_size,
                              hipStream_t stream) {
    const float* h      = (const float*)d_in[0];
    const float* raw    = (const float*)d_in[1];
    const float* offset = (const float*)d_in[2];
    const float* scale  = (const float*)d_in[3];
    float* out = (float*)d_out;
    int T = in_sizes[0];
    int NCH = (T + CL - 1) / CL;                 // 63 chunks at T=2000
    const int NB = (NCH > 64) ? NCH : 64;        // >=64 for G columns

    // ws carve-up (16B-aligned)
    char* ws = (char*)d_ws;
    size_t o = 0;
    int2* lohi = (int2*)(ws + o); o += (size_t)NCH * 256 * 8;
    float* Gg  = (float*)(ws + o);               // GSZ*4 = 132608 B

    void* args[] = { (void*)&h, (void*)&raw, (void*)&scale, (void*)&offset,
                     (void*)&out, (void*)&lohi, (void*)&Gg, (void*)&T, (void*)&NCH };
    hipLaunchCooperativeKernel((const void*)hyst_fused, dim3(NB), dim3(256),
                               args, 0, stream);
}

// Round 7
// 75.702 us; speedup vs baseline: 1.4216x; 1.4216x over previous
//
#include <hip/hip_runtime.h>
#include <math.h>

// Preisach hysteresis, N=256, parallel-in-time clamp-scan, 2 dispatches.
// (R6's cooperative single-dispatch REGRESSED: grid.sync() across XCDs cost
//  ~30+ us — more than the launch gap it saved. Two plain dispatches win.)
//
// Per row r the state is a staircase: +1 for j<=c_r, -1 for c_r<j<=r.
// Step update: c = max(min(c, k_t), r_t) with
//   up   (h>hp): k=256, r_t = (row < u_t ? row : -1), u_t = #{i : i*d < h}
//   down (h<hp): k = max{j : j*d <= h}, r_t = -1
// Clamps compose: chunk of steps == c -> max(min(c,HI),LO), (LO,HI) = chunk
// run on seeds (-1, 256).
//   K1: per-chunk codes + per-row (LO,HI); packed G table build (global ws)
//   K3: 1 chunk/block (63 blocks x 256 thr, 1 row/thread): stage G to LDS,
//       entry scan over prior chunks' lohi (1 coalesced int2 + 2 med3 each),
//       32-step replay (1 lane-private gather/step) + 64-lane butterfly;
//       4 wave-partials combined via 512 B LDS. No atomics.
//
// Packed G column i holds rows {i, 255-i, 64+i, 191-i} = exactly 518 floats:
//   row i     : idx0 = 0        row 255-i : idx0 = i+2
//   row 64+i  : idx0 = 259      row 191-i : idx0 = 325+i
// addr = idx*64 + col.  G_r[e] = 2*P_r(e-1) - Tot_r, e in [0, r+1],
// P = prefix sums of softplus(raw row r).

#define CL 32               // chunk length (time steps per chunk)
#define GSZ (518 * 64)      // packed G table, floats (132608 B)

__device__ __forceinline__ int make_code(const float* __restrict__ h, int t, int T) {
    const float delta = 1.0f / 255.0f;          // fl(1/255), matches jnp.linspace
    int code = 256;                              // no-op: k=256, u=0
    if (t < T) {
        const float hc = h[t];
        const float hp = (t == 0) ? 0.0f : h[t - 1];
        if (hc > hp) {
            // u-1 = max{ i : (float)i*delta < hc }   (yy >= h keeps state)
            int i2 = (int)(hc * 255.0f);
            if (i2 > 255) i2 = 255;
            while (i2 < 255 && (float)(i2 + 1) * delta < hc) ++i2;
            while (i2 >= 0 && (float)i2 * delta >= hc) --i2;
            code = ((i2 + 1) << 16) | 256;
        } else if (hc < hp) {
            // k = max{ j : (float)j*delta <= hc }    (xx <= h keeps state)
            int kk = (int)(hc * 255.0f);
            if (kk > 255) kk = 255;
            while (kk < 255 && (float)(kk + 1) * delta <= hc) ++kk;
            while (kk > 0 && (float)kk * delta > hc) --kk;
            code = kk;
        }
    }
    return code;
}

// ---- K1: blocks [0,NB1): codes + per-row clamp compose (1 chunk per wave)
//          blocks [NB1, NB1+64): G build (1 row per wave)
__global__ __launch_bounds__(256)
void k1_compose_gbuild(const float* __restrict__ h, const float* __restrict__ raw,
                       int* __restrict__ codes, int2* __restrict__ lohi,
                       float* __restrict__ Gg, int T, int NCH, int NB1) {
    const int b = blockIdx.x;
    const int tid = threadIdx.x;
    const int w = tid >> 6, l = tid & 63;
    if (b < NB1) {
        const int q = b * 4 + w;                 // chunk for this wave
        if (q >= NCH) return;
        int mycode = 256;
        if (l < CL) {
            mycode = make_code(h, q * CL + l, T);
            codes[q * CL + l] = mycode;
        }
        // compose chunk clamp for rows r = 64*j + l (shfl-broadcast the codes)
        int lo[4] = {-1, -1, -1, -1}, hi[4] = {256, 256, 256, 256};
        #pragma unroll
        for (int s = 0; s < CL; ++s) {
            const int cd = __shfl(mycode, s);
            const int k = cd & 0xFFFF, u = cd >> 16;
            #pragma unroll
            for (int j = 0; j < 4; ++j) {
                const int r = j * 64 + l;
                const int rr = (r < u) ? r : -1;
                lo[j] = max(min(lo[j], k), rr);
                hi[j] = max(min(hi[j], k), rr);
            }
        }
        #pragma unroll
        for (int j = 0; j < 4; ++j)
            lohi[q * 256 + j * 64 + l] = make_int2(lo[j], hi[j]);
    } else {
        // ---- G build: wave (b-NB1)*4 + w builds row r
        const int r = (b - NB1) * 4 + w;
        const int tri = r * (r + 1) / 2;
        int lcol, idx0;
        if (r < 64)       { lcol = r;       idx0 = 0; }
        else if (r < 128) { lcol = r - 64;  idx0 = 259; }
        else if (r < 192) { lcol = 191 - r; idx0 = 325 + lcol; }
        else              { lcol = 255 - r; idx0 = lcol + 2; }

        float Pseg[4];
        float carry = 0.0f;
        const int nseg = r / 64 + 1;
        #pragma unroll
        for (int s = 0; s < 4; ++s) {
            Pseg[s] = 0.0f;
            if (s < nseg) {
                const int j = s * 64 + l;
                float v = 0.0f;
                if (j <= r) {
                    const float x = raw[tri + j];
                    // jax.nn.softplus(x) = max(x,0) + log1p(exp(-|x|))
                    v = fmaxf(x, 0.0f) + log1pf(expf(-fabsf(x)));
                }
                #pragma unroll
                for (int off = 1; off < 64; off <<= 1) {
                    const float t2 = __shfl_up(v, off);
                    if (l >= off) v += t2;
                }
                Pseg[s] = carry + v;             // inclusive prefix P_j
                carry += __shfl(v, 63);          // segment total
            }
        }
        const float tot = carry;
        if (l == 0) Gg[idx0 * 64 + lcol] = -tot;             // e=0: 2*P(-1)-Tot
        #pragma unroll
        for (int s = 0; s < 4; ++s) {
            const int j = s * 64 + l;
            if (j <= r) Gg[(idx0 + 1 + j) * 64 + lcol] = 2.0f * Pseg[s] - tot;
        }
    }
}

// ---- K3: 1 chunk per block, 1 row per thread; entry scan + replay + out
__global__ __launch_bounds__(256)
void k3_eval(const int* __restrict__ codes, const int2* __restrict__ lohi,
             const float* __restrict__ Gg,
             const float* __restrict__ scale, const float* __restrict__ offset,
             float* __restrict__ out, int T, int NCH) {
    __shared__ __align__(16) float Gl[GSZ];      // 132608 B
    __shared__ int cds[CL];
    __shared__ float cb[4 * CL];                 // per-wave step partials

    const int tid = threadIdx.x;
    const int w = tid >> 6, l = tid & 63;
    const int q = blockIdx.x;                    // chunk
    const int r = tid;                           // this thread's row

    // stage G: coalesced float4 copy, all 256 threads (8288 vec4)
    {
        const float4* __restrict__ Gf4 = (const float4*)Gg;
        float4* Gl4 = (float4*)Gl;
        #pragma unroll 4
        for (int j = tid; j < GSZ / 4; j += 256) Gl4[j] = Gf4[j];
    }
    if (tid < CL) cds[tid] = codes[q * CL + tid];

    // entry state for row r: compose prior chunks (coalesced int2 loads)
    int c = -1;
    #pragma unroll 4
    for (int j = 0; j < q; ++j) {
        const int2 lh = lohi[j * 256 + r];
        c = max(min(c, lh.y), lh.x);
    }
    __syncthreads();                             // staging + cds visible

    // gather address: Gl[(gbase + c)*64 + lcol], lane-private column (2-way)
    int gbase, lcol;
    if (w == 0)      { gbase = 1;        lcol = l; }        // row l
    else if (w == 1) { gbase = 260;      lcol = l; }        // row 64+l
    else if (w == 2) { gbase = 389 - l;  lcol = 63 - l; }   // row 128+l = 191-i
    else             { gbase = 66 - l;   lcol = 63 - l; }   // row 192+l = 255-i

    // replay: per-step gather + 64-lane butterfly; lane s keeps step s
    float myout = 0.0f;
    #pragma unroll 4
    for (int s = 0; s < CL; ++s) {
        const int cd = cds[s];                   // uniform -> LDS broadcast
        const int k = cd & 0xFFFF, u = cd >> 16;
        c = max(min(c, k), (r < u) ? r : -1);
        float p = Gl[(gbase + c) * 64 + lcol];
        #pragma unroll
        for (int off = 32; off; off >>= 1) p += __shfl_xor(p, off);
        if (l == s) myout = p;
    }
    if (l < CL) cb[w * CL + l] = myout;
    __syncthreads();
    if (w == 0 && l < CL) {
        const int t = q * CL + l;
        if (t < T) {
            const float sum = cb[l] + cb[CL + l] + cb[2 * CL + l] + cb[3 * CL + l];
            out[t] = sum * (1.0f / 32896.0f) * scale[0] + offset[0];
        }
    }
}

extern "C" void kernel_launch(void* const* d_in, const int* in_sizes, int n_in,
                              void* d_out, int out_size, void* d_ws, size_t ws_size,
                              hipStream_t stream) {
    const float* h      = (const float*)d_in[0];
    const float* raw    = (const float*)d_in[1];
    const float* offset = (const float*)d_in[2];
    const float* scale  = (const float*)d_in[3];
    float* out = (float*)d_out;
    const int T = in_sizes[0];
    const int NCH = (T + CL - 1) / CL;           // 63 chunks at T=2000
    const int NB1 = (NCH + 3) / 4;               // 4 chunks (waves) per k1 block

    // ws carve-up (16B-aligned)
    char* ws = (char*)d_ws;
    size_t o = 0;
    int* codes = (int*)(ws + o);  o += ((size_t)NCH * CL * 4 + 15) & ~15ull;
    int2* lohi = (int2*)(ws + o); o += (size_t)NCH * 256 * 8;
    float* Gg  = (float*)(ws + o);               // GSZ*4 = 132608 B

    k1_compose_gbuild<<<NB1 + 64, 256, 0, stream>>>(h, raw, codes, lohi, Gg, T, NCH, NB1);
    k3_eval<<<NCH, 256, 0, stream>>>(codes, lohi, Gg, scale, offset, out, T, NCH);
}

// Round 8
// 73.096 us; speedup vs baseline: 1.4723x; 1.0356x over previous
//
#include <hip/hip_runtime.h>
#include <math.h>

// Preisach hysteresis, N=256, parallel-in-time clamp-scan, 2 dispatches.
// (R6 cooperative single-dispatch REGRESSED — grid.sync() cost > launch gap.)
//
// Per row r the state is a staircase: +1 for j<=c_r, -1 for c_r<j<=r.
// Step update: c = max(min(c, k_t), r_t) with
//   up   (h>hp): k=256, r_t = (row < u_t ? row : -1), u_t = #{i : i*d < h}
//   down (h<hp): k = max{j : j*d <= h}, r_t = -1
// Clamps compose: chunk of steps == c -> max(min(c,HI),LO), (LO,HI) = chunk
// run on seeds (-1, 256).
//   K1: per-chunk codes + per-row (LO,HI); packed G table build (global ws)
//   K3: 1 chunk/block (63 blocks x 256 thr, 1 row/thread):
//       async-DMA G to LDS (global_load_lds w=16) OVERLAPPED with the
//       entry-state scan over prior chunks' lohi; then 32-step replay
//       (1 lane-private gather/step) + 64-lane butterfly; 4 wave-partials
//       combined via 512 B LDS. No atomics.
//
// Packed G column i holds rows {i, 255-i, 64+i, 191-i} = exactly 518 floats:
//   row i     : idx0 = 0        row 255-i : idx0 = i+2
//   row 64+i  : idx0 = 259      row 191-i : idx0 = 325+i
// addr = idx*64 + col.  G_r[e] = 2*P_r(e-1) - Tot_r, e in [0, r+1],
// P = prefix sums of softplus(raw row r).

#define CL 32               // chunk length (time steps per chunk)
#define GSZ (518 * 64)      // packed G table, floats (132608 B; 8288 float4)
#define GDMA_BYTES 131072   // DMA'd portion: 32 iters x 256 lanes x 16 B
#define AS1 __attribute__((address_space(1)))
#define AS3 __attribute__((address_space(3)))

__device__ __forceinline__ int make_code(const float* __restrict__ h, int t, int T) {
    const float delta = 1.0f / 255.0f;          // fl(1/255), matches jnp.linspace
    int code = 256;                              // no-op: k=256, u=0
    if (t < T) {
        const float hc = h[t];
        const float hp = (t == 0) ? 0.0f : h[t - 1];
        if (hc > hp) {
            // u-1 = max{ i : (float)i*delta < hc }   (yy >= h keeps state)
            int i2 = (int)(hc * 255.0f);
            if (i2 > 255) i2 = 255;
            while (i2 < 255 && (float)(i2 + 1) * delta < hc) ++i2;
            while (i2 >= 0 && (float)i2 * delta >= hc) --i2;
            code = ((i2 + 1) << 16) | 256;
        } else if (hc < hp) {
            // k = max{ j : (float)j*delta <= hc }    (xx <= h keeps state)
            int kk = (int)(hc * 255.0f);
            if (kk > 255) kk = 255;
            while (kk < 255 && (float)(kk + 1) * delta <= hc) ++kk;
            while (kk > 0 && (float)kk * delta > hc) --kk;
            code = kk;
        }
    }
    return code;
}

// ---- K1: blocks [0,NB1): codes + per-row clamp compose (1 chunk per wave)
//          blocks [NB1, NB1+64): G build (1 row per wave)
__global__ __launch_bounds__(256)
void k1_compose_gbuild(const float* __restrict__ h, const float* __restrict__ raw,
                       int* __restrict__ codes, int2* __restrict__ lohi,
                       float* __restrict__ Gg, int T, int NCH, int NB1) {
    const int b = blockIdx.x;
    const int tid = threadIdx.x;
    const int w = tid >> 6, l = tid & 63;
    if (b < NB1) {
        const int q = b * 4 + w;                 // chunk for this wave
        if (q >= NCH) return;
        int mycode = 256;
        if (l < CL) {
            mycode = make_code(h, q * CL + l, T);
            codes[q * CL + l] = mycode;
        }
        // compose chunk clamp for rows r = 64*j + l (shfl-broadcast the codes)
        int lo[4] = {-1, -1, -1, -1}, hi[4] = {256, 256, 256, 256};
        #pragma unroll
        for (int s = 0; s < CL; ++s) {
            const int cd = __shfl(mycode, s);
            const int k = cd & 0xFFFF, u = cd >> 16;
            #pragma unroll
            for (int j = 0; j < 4; ++j) {
                const int r = j * 64 + l;
                const int rr = (r < u) ? r : -1;
                lo[j] = max(min(lo[j], k), rr);
                hi[j] = max(min(hi[j], k), rr);
            }
        }
        #pragma unroll
        for (int j = 0; j < 4; ++j)
            lohi[q * 256 + j * 64 + l] = make_int2(lo[j], hi[j]);
    } else {
        // ---- G build: wave (b-NB1)*4 + w builds row r
        const int r = (b - NB1) * 4 + w;
        const int tri = r * (r + 1) / 2;
        int lcol, idx0;
        if (r < 64)       { lcol = r;       idx0 = 0; }
        else if (r < 128) { lcol = r - 64;  idx0 = 259; }
        else if (r < 192) { lcol = 191 - r; idx0 = 325 + lcol; }
        else              { lcol = 255 - r; idx0 = lcol + 2; }

        float Pseg[4];
        float carry = 0.0f;
        const int nseg = r / 64 + 1;
        #pragma unroll
        for (int s = 0; s < 4; ++s) {
            Pseg[s] = 0.0f;
            if (s < nseg) {
                const int j = s * 64 + l;
                float v = 0.0f;
                if (j <= r) {
                    const float x = raw[tri + j];
                    // jax.nn.softplus(x) = max(x,0) + log1p(exp(-|x|))
                    v = fmaxf(x, 0.0f) + log1pf(expf(-fabsf(x)));
                }
                #pragma unroll
                for (int off = 1; off < 64; off <<= 1) {
                    const float t2 = __shfl_up(v, off);
                    if (l >= off) v += t2;
                }
                Pseg[s] = carry + v;             // inclusive prefix P_j
                carry += __shfl(v, 63);          // segment total
            }
        }
        const float tot = carry;
        if (l == 0) Gg[idx0 * 64 + lcol] = -tot;             // e=0: 2*P(-1)-Tot
        #pragma unroll
        for (int s = 0; s < 4; ++s) {
            const int j = s * 64 + l;
            if (j <= r) Gg[(idx0 + 1 + j) * 64 + lcol] = 2.0f * Pseg[s] - tot;
        }
    }
}

// ---- K3: 1 chunk per block, 1 row per thread; DMA staging || entry scan,
//          then replay + butterfly + out
__global__ __launch_bounds__(256)
void k3_eval(const int* __restrict__ codes, const int2* __restrict__ lohi,
             const float* __restrict__ Gg,
             const float* __restrict__ scale, const float* __restrict__ offset,
             float* __restrict__ out, int T, int NCH) {
    __shared__ __align__(16) float Gl[GSZ];      // 132608 B
    __shared__ int cds[CL];
    __shared__ float cb[4 * CL];                 // per-wave step partials

    const int tid = threadIdx.x;
    const int w = tid >> 6, l = tid & 63;
    const int q = blockIdx.x;                    // chunk
    const int r = tid;                           // this thread's row

    // chunk codes: issue early (in-order vmcnt, lands before DMA drain)
    if (tid < CL) cds[tid] = codes[q * CL + tid];

    // ---- async G staging: direct global->LDS DMA, 16 B/lane/instr.
    // dest = wave-uniform LDS base + lane*16 (m104); our flat copy layout is
    // exactly lane-contiguous. 32 iters x 4 waves x 1024 B = 131072 B.
    {
        const char* gsrc = (const char*)Gg;
        char* lbase = (char*)Gl;
        #pragma unroll 8
        for (int it = 0; it < 32; ++it) {
            const int off = it * 4096 + w * 1024;
            __builtin_amdgcn_global_load_lds(
                (const AS1 void*)(gsrc + off + l * 16),
                (AS3 void*)(lbase + off), 16, 0, 0);
        }
        // remainder: floats 32768..33151 (96 float4), plain copy
        if (tid < 96) {
            const float4* __restrict__ Gf4 = (const float4*)Gg;
            ((float4*)Gl)[8192 + tid] = Gf4[8192 + tid];
        }
    }

    // ---- entry state for row r: compose prior chunks (overlaps DMA drain)
    int c = -1;
    #pragma unroll 8
    for (int j = 0; j < q; ++j) {
        const int2 lh = lohi[j * 256 + r];
        c = max(min(c, lh.y), lh.x);
    }
    __syncthreads();                             // drains DMA (vmcnt) + cds

    // gather address: Gl[(gbase + c)*64 + lcol], lane-private column (2-way)
    int gbase, lcol;
    if (w == 0)      { gbase = 1;        lcol = l; }        // row l
    else if (w == 1) { gbase = 260;      lcol = l; }        // row 64+l
    else if (w == 2) { gbase = 389 - l;  lcol = 63 - l; }   // row 128+l = 191-i
    else             { gbase = 66 - l;   lcol = 63 - l; }   // row 192+l = 255-i

    // replay: per-step gather + 64-lane butterfly; lane s keeps step s
    float myout = 0.0f;
    #pragma unroll 4
    for (int s = 0; s < CL; ++s) {
        const int cd = cds[s];                   // uniform -> LDS broadcast
        const int k = cd & 0xFFFF, u = cd >> 16;
        c = max(min(c, k), (r < u) ? r : -1);
        float p = Gl[(gbase + c) * 64 + lcol];
        #pragma unroll
        for (int off = 32; off; off >>= 1) p += __shfl_xor(p, off);
        if (l == s) myout = p;
    }
    if (l < CL) cb[w * CL + l] = myout;
    __syncthreads();
    if (w == 0 && l < CL) {
        const int t = q * CL + l;
        if (t < T) {
            const float sum = cb[l] + cb[CL + l] + cb[2 * CL + l] + cb[3 * CL + l];
            out[t] = sum * (1.0f / 32896.0f) * scale[0] + offset[0];
        }
    }
}

extern "C" void kernel_launch(void* const* d_in, const int* in_sizes, int n_in,
                              void* d_out, int out_size, void* d_ws, size_t ws_size,
                              hipStream_t stream) {
    const float* h      = (const float*)d_in[0];
    const float* raw    = (const float*)d_in[1];
    const float* offset = (const float*)d_in[2];
    const float* scale  = (const float*)d_in[3];
    float* out = (float*)d_out;
    const int T = in_sizes[0];
    const int NCH = (T + CL - 1) / CL;           // 63 chunks at T=2000
    const int NB1 = (NCH + 3) / 4;               // 4 chunks (waves) per k1 block

    // ws carve-up (16B-aligned)
    char* ws = (char*)d_ws;
    size_t o = 0;
    int* codes = (int*)(ws + o);  o += ((size_t)NCH * CL * 4 + 15) & ~15ull;
    int2* lohi = (int2*)(ws + o); o += (size_t)NCH * 256 * 8;
    float* Gg  = (float*)(ws + o);               // GSZ*4 = 132608 B

    k1_compose_gbuild<<<NB1 + 64, 256, 0, stream>>>(h, raw, codes, lohi, Gg, T, NCH, NB1);
    k3_eval<<<NCH, 256, 0, stream>>>(codes, lohi, Gg, scale, offset, out, T, NCH);
}

// Round 9
// 71.007 us; speedup vs baseline: 1.5156x; 1.0294x over previous
//
#include <hip/hip_runtime.h>
#include <math.h>

// Preisach hysteresis, N=256, parallel-in-time clamp-scan, 2 dispatches.
// (R6 cooperative single-dispatch REGRESSED — grid.sync() cost > launch gap.)
//
// Per row r the state is a staircase: +1 for j<=c_r, -1 for c_r<j<=r.
// Step update: c = max(min(c, k_t), r_t) with
//   up   (h>hp): k=256, r_t = (row < u_t ? row : -1), u_t = #{i : i*d < h}
//   down (h<hp): k = max{j : j*d <= h}, r_t = -1
// Clamps compose associatively: chunk == c -> max(min(c,HI),LO), (LO,HI) =
// chunk run on seeds (-1, 256); groups of 4 chunks likewise (glohi).
//   K1: per-chunk codes + per-row (LO,HI) + per-GROUP (LO,HI) via LDS;
//       packed G table build (global ws)
//   K3: 1 chunk/block (63 blocks x 256 thr, 1 row/thread):
//       async-DMA G to LDS (global_load_lds w=16) OVERLAPPED with the
//       entry-state scan (<=15 group + <=3 chunk clamp loads, was <=62);
//       32-step replay (1 lane-private gather/step) + 64-lane butterfly;
//       4 wave-partials combined via 512 B LDS. No atomics.
//
// Packed G column i holds rows {i, 255-i, 64+i, 191-i} = exactly 518 floats:
//   row i     : idx0 = 0        row 255-i : idx0 = i+2
//   row 64+i  : idx0 = 259      row 191-i : idx0 = 325+i
// addr = idx*64 + col.  G_r[e] = 2*P_r(e-1) - Tot_r, e in [0, r+1],
// P = prefix sums of softplus(raw row r).

#define CL 32               // chunk length (time steps per chunk)
#define GSZ (518 * 64)      // packed G table, floats (132608 B; 8288 float4)
#define AS1 __attribute__((address_space(1)))
#define AS3 __attribute__((address_space(3)))

__device__ __forceinline__ int make_code(const float* __restrict__ h, int t, int T) {
    const float delta = 1.0f / 255.0f;          // fl(1/255), matches jnp.linspace
    int code = 256;                              // no-op: k=256, u=0
    if (t < T) {
        const float hc = h[t];
        const float hp = (t == 0) ? 0.0f : h[t - 1];
        if (hc > hp) {
            // u-1 = max{ i : (float)i*delta < hc }   (yy >= h keeps state)
            int i2 = (int)(hc * 255.0f);
            if (i2 > 255) i2 = 255;
            while (i2 < 255 && (float)(i2 + 1) * delta < hc) ++i2;
            while (i2 >= 0 && (float)i2 * delta >= hc) --i2;
            code = ((i2 + 1) << 16) | 256;
        } else if (hc < hp) {
            // k = max{ j : (float)j*delta <= hc }    (xx <= h keeps state)
            int kk = (int)(hc * 255.0f);
            if (kk > 255) kk = 255;
            while (kk < 255 && (float)(kk + 1) * delta <= hc) ++kk;
            while (kk > 0 && (float)kk * delta > hc) --kk;
            code = kk;
        }
    }
    return code;
}

// ---- K1: blocks [0,NB1): codes + per-row chunk (LO,HI) + group (LO,HI)
//          blocks [NB1, NB1+64): G build (1 row per wave)
__global__ __launch_bounds__(256)
void k1_compose_gbuild(const float* __restrict__ h, const float* __restrict__ raw,
                       int* __restrict__ codes, int2* __restrict__ lohi,
                       int2* __restrict__ glohi, float* __restrict__ Gg,
                       int T, int NCH, int NB1) {
    const int b = blockIdx.x;
    const int tid = threadIdx.x;
    const int w = tid >> 6, l = tid & 63;
    if (b < NB1) {
        __shared__ int2 slh[4][256];             // per-chunk clamps, 8 KB
        const int q = b * 4 + w;                 // chunk for this wave
        int mycode = 256;                        // no-op (q>=NCH -> identity)
        if (q < NCH && l < CL) {
            mycode = make_code(h, q * CL + l, T);
            codes[q * CL + l] = mycode;
        }
        // compose chunk clamp for rows r = 64*j + l (shfl-broadcast the codes)
        int lo[4] = {-1, -1, -1, -1}, hi[4] = {256, 256, 256, 256};
        #pragma unroll
        for (int s = 0; s < CL; ++s) {
            const int cd = __shfl(mycode, s);
            const int k = cd & 0xFFFF, u = cd >> 16;
            #pragma unroll
            for (int j = 0; j < 4; ++j) {
                const int r = j * 64 + l;
                const int rr = (r < u) ? r : -1;
                lo[j] = max(min(lo[j], k), rr);
                hi[j] = max(min(hi[j], k), rr);
            }
        }
        #pragma unroll
        for (int j = 0; j < 4; ++j) {
            slh[w][j * 64 + l] = make_int2(lo[j], hi[j]);
            if (q < NCH) lohi[q * 256 + j * 64 + l] = make_int2(lo[j], hi[j]);
        }
        __syncthreads();
        // group clamp: thread = row; compose the block's 4 chunks in order
        int glo = -1, ghi = 256;
        #pragma unroll
        for (int w2 = 0; w2 < 4; ++w2) {
            const int2 lh = slh[w2][tid];        // stride-2 banks: free
            glo = max(min(glo, lh.y), lh.x);
            ghi = max(min(ghi, lh.y), lh.x);
        }
        glohi[b * 256 + tid] = make_int2(glo, ghi);
    } else {
        // ---- G build: wave (b-NB1)*4 + w builds row r
        const int r = (b - NB1) * 4 + w;
        const int tri = r * (r + 1) / 2;
        int lcol, idx0;
        if (r < 64)       { lcol = r;       idx0 = 0; }
        else if (r < 128) { lcol = r - 64;  idx0 = 259; }
        else if (r < 192) { lcol = 191 - r; idx0 = 325 + lcol; }
        else              { lcol = 255 - r; idx0 = lcol + 2; }

        float Pseg[4];
        float carry = 0.0f;
        const int nseg = r / 64 + 1;
        #pragma unroll
        for (int s = 0; s < 4; ++s) {
            Pseg[s] = 0.0f;
            if (s < nseg) {
                const int j = s * 64 + l;
                float v = 0.0f;
                if (j <= r) {
                    const float x = raw[tri + j];
                    // jax.nn.softplus(x) = max(x,0) + log1p(exp(-|x|))
                    v = fmaxf(x, 0.0f) + log1pf(expf(-fabsf(x)));
                }
                #pragma unroll
                for (int off = 1; off < 64; off <<= 1) {
                    const float t2 = __shfl_up(v, off);
                    if (l >= off) v += t2;
                }
                Pseg[s] = carry + v;             // inclusive prefix P_j
                carry += __shfl(v, 63);          // segment total
            }
        }
        const float tot = carry;
        if (l == 0) Gg[idx0 * 64 + lcol] = -tot;             // e=0: 2*P(-1)-Tot
        #pragma unroll
        for (int s = 0; s < 4; ++s) {
            const int j = s * 64 + l;
            if (j <= r) Gg[(idx0 + 1 + j) * 64 + lcol] = 2.0f * Pseg[s] - tot;
        }
    }
}

// ---- K3: 1 chunk per block, 1 row per thread; DMA staging || entry scan,
//          then replay + butterfly + out
__global__ __launch_bounds__(256)
void k3_eval(const int* __restrict__ codes, const int2* __restrict__ lohi,
             const int2* __restrict__ glohi, const float* __restrict__ Gg,
             const float* __restrict__ scale, const float* __restrict__ offset,
             float* __restrict__ out, int T, int NCH) {
    __shared__ __align__(16) float Gl[GSZ];      // 132608 B
    __shared__ int cds[CL];
    __shared__ float cb[4 * CL];                 // per-wave step partials

    const int tid = threadIdx.x;
    const int w = tid >> 6, l = tid & 63;
    const int q = blockIdx.x;                    // chunk
    const int r = tid;                           // this thread's row

    // chunk codes: issue early (in-order vmcnt, lands before DMA drain)
    if (tid < CL) cds[tid] = codes[q * CL + tid];

    // ---- async G staging: direct global->LDS DMA, 16 B/lane/instr.
    // dest = wave-uniform LDS base + lane*16 (m104); flat layout matches.
    // 32 iters x 4 waves x 1024 B = 131072 B; 96-float4 remainder plain.
    {
        const char* gsrc = (const char*)Gg;
        char* lbase = (char*)Gl;
        #pragma unroll 8
        for (int it = 0; it < 32; ++it) {
            const int off = it * 4096 + w * 1024;
            __builtin_amdgcn_global_load_lds(
                (const AS1 void*)(gsrc + off + l * 16),
                (AS3 void*)(lbase + off), 16, 0, 0);
        }
        if (tid < 96) {
            const float4* __restrict__ Gf4 = (const float4*)Gg;
            ((float4*)Gl)[8192 + tid] = Gf4[8192 + tid];
        }
    }

    // ---- entry state for row r: g group clamps + (q&3) chunk clamps
    // (bit-identical to composing all q chunk clamps left-to-right)
    int c = -1;
    {
        const int g = q >> 2;
        #pragma unroll 8
        for (int j = 0; j < g; ++j) {
            const int2 lh = glohi[j * 256 + r];
            c = max(min(c, lh.y), lh.x);
        }
        #pragma unroll
        for (int j = g * 4; j < q; ++j) {
            const int2 lh = lohi[j * 256 + r];
            c = max(min(c, lh.y), lh.x);
        }
    }
    __syncthreads();                             // drains DMA (vmcnt) + cds

    // gather address: Gl[(gbase + c)*64 + lcol], lane-private column (2-way)
    int gbase, lcol;
    if (w == 0)      { gbase = 1;        lcol = l; }        // row l
    else if (w == 1) { gbase = 260;      lcol = l; }        // row 64+l
    else if (w == 2) { gbase = 389 - l;  lcol = 63 - l; }   // row 128+l = 191-i
    else             { gbase = 66 - l;   lcol = 63 - l; }   // row 192+l = 255-i

    // replay: per-step gather + 64-lane butterfly; lane s keeps step s
    float myout = 0.0f;
    #pragma unroll 4
    for (int s = 0; s < CL; ++s) {
        const int cd = cds[s];                   // uniform -> LDS broadcast
        const int k = cd & 0xFFFF, u = cd >> 16;
        c = max(min(c, k), (r < u) ? r : -1);
        float p = Gl[(gbase + c) * 64 + lcol];
        #pragma unroll
        for (int off = 32; off; off >>= 1) p += __shfl_xor(p, off);
        if (l == s) myout = p;
    }
    if (l < CL) cb[w * CL + l] = myout;
    __syncthreads();
    if (w == 0 && l < CL) {
        const int t = q * CL + l;
        if (t < T) {
            const float sum = cb[l] + cb[CL + l] + cb[2 * CL + l] + cb[3 * CL + l];
            out[t] = sum * (1.0f / 32896.0f) * scale[0] + offset[0];
        }
    }
}

extern "C" void kernel_launch(void* const* d_in, const int* in_sizes, int n_in,
                              void* d_out, int out_size, void* d_ws, size_t ws_size,
                              hipStream_t stream) {
    const float* h      = (const float*)d_in[0];
    const float* raw    = (const float*)d_in[1];
    const float* offset = (const float*)d_in[2];
    const float* scale  = (const float*)d_in[3];
    float* out = (float*)d_out;
    const int T = in_sizes[0];
    const int NCH = (T + CL - 1) / CL;           // 63 chunks at T=2000
    const int NB1 = (NCH + 3) / 4;               // 4 chunks (waves) per k1 block

    // ws carve-up (16B-aligned)
    char* ws = (char*)d_ws;
    size_t o = 0;
    int* codes  = (int*)(ws + o);  o += ((size_t)NCH * CL * 4 + 15) & ~15ull;
    int2* lohi  = (int2*)(ws + o); o += (size_t)NCH * 256 * 8;
    int2* glohi = (int2*)(ws + o); o += (size_t)NB1 * 256 * 8;
    float* Gg   = (float*)(ws + o);              // GSZ*4 = 132608 B

    k1_compose_gbuild<<<NB1 + 64, 256, 0, stream>>>(h, raw, codes, lohi, glohi,
                                                    Gg, T, NCH, NB1);
    k3_eval<<<NCH, 256, 0, stream>>>(codes, lohi, glohi, Gg, scale, offset,
                                     out, T, NCH);
}